// Round 12
// baseline (511.849 us; speedup 1.0000x reference)
//
#include <hip/hip_runtime.h>

#define NPIX  (1024 * 1024)
#define NVEC  (NPIX / 4)
#define NSTAT 21
#define RBLOCKS  128   // partial blocks per batch (must equal solve block size)
#define RTHREADS 256
// NVEC / (RBLOCKS*RTHREADS) == 8 tiles exactly
#define RITERS (NVEC / (RBLOCKS * RTHREADS))
#define RSTRIDE (RBLOCKS * RTHREADS)
#define TILE 256       // float4 slots per plane per tile (4 KB/plane, 24 KB/tile)

// ---------------------------------------------------------------------------
// Pass 1 (round 12 redesign): DMA-staged single-stream-per-wave reads.
// Rounds 4/5/10/11 proved per-wave MLP is NOT the limiter (137 µs invariant
// under naive / C++-prefetch / asm-pinned 12-deep schedules). Remaining
// hypothesis: 6 interleaved per-wave read streams defeat the memory system.
// Here each wave issues ONE contiguous 1 KB global_load_lds per plane per
// tile (6 DMA instrs/wave/tile), double-buffered (T3/T4: counted vmcnt(6),
// raw s_barrier — NOT __syncthreads, which drains vmcnt to 0).
// Ledger (per wave): STAGE=6 instr. prologue 6 out; each iter: STAGE next
// (12 out) -> vmcnt(6) (current tile landed) -> barrier -> consume -> barrier
// (protects buffer reuse: tile k+2 overwrites buf k&1, issued only after all
// waves finished reading tile k). Tail: vmcnt(0).
// Consumption: thread t reads stage[buf][pl][t] (contiguous ds_read_b128,
// conflict-free) -> same pixel->thread mapping as rounds 4-11, bit-identical
// stats. fp32 accumulators (32 px/thread), fp64 from wave reduction onward.
// ---------------------------------------------------------------------------
__device__ __forceinline__ void gld_lds16(const float4* g, float4* l) {
    __builtin_amdgcn_global_load_lds(
        (const __attribute__((address_space(1))) void*)(g),
        (__attribute__((address_space(3))) void*)(l),
        16, 0, 0);
}

__global__ __launch_bounds__(RTHREADS, 2) void reduce_stats(
    const float4* __restrict__ src, const float4* __restrict__ dst,
    double* __restrict__ partials)
{
    const int b  = blockIdx.y;
    const int pb = blockIdx.x;
    const int wv = threadIdx.x >> 6;
    const int ln = threadIdx.x & 63;

    const float4* P[6];
    P[0] = src + (size_t)b * 3 * NVEC;
    P[1] = P[0] + NVEC;
    P[2] = P[0] + 2 * NVEC;
    P[3] = dst + (size_t)b * 3 * NVEC;
    P[4] = P[3] + NVEC;
    P[5] = P[3] + 2 * NVEC;

    __shared__ float4 stage[2][6][TILE];   // 48 KB

    float acc[NSTAT];
#pragma unroll
    for (int s = 0; s < NSTAT; ++s) acc[s] = 0.0f;

#define ACC1(A0v, A1v, A2v, B0v, B1v, B2v)                                   \
    do {                                                                     \
        acc[0] += (A0v); acc[1] += (A1v); acc[2] += (A2v);                   \
        acc[3] += (B0v); acc[4] += (B1v); acc[5] += (B2v);                   \
        acc[6]  = fmaf((A0v), (A0v), acc[6]);                                \
        acc[7]  = fmaf((A0v), (A1v), acc[7]);                                \
        acc[8]  = fmaf((A0v), (A2v), acc[8]);                                \
        acc[9]  = fmaf((A1v), (A1v), acc[9]);                                \
        acc[10] = fmaf((A1v), (A2v), acc[10]);                               \
        acc[11] = fmaf((A2v), (A2v), acc[11]);                               \
        acc[12] = fmaf((B0v), (A0v), acc[12]);                               \
        acc[13] = fmaf((B0v), (A1v), acc[13]);                               \
        acc[14] = fmaf((B0v), (A2v), acc[14]);                               \
        acc[15] = fmaf((B1v), (A0v), acc[15]);                               \
        acc[16] = fmaf((B1v), (A1v), acc[16]);                               \
        acc[17] = fmaf((B1v), (A2v), acc[17]);                               \
        acc[18] = fmaf((B2v), (A0v), acc[18]);                               \
        acc[19] = fmaf((B2v), (A1v), acc[19]);                               \
        acc[20] = fmaf((B2v), (A2v), acc[20]);                               \
    } while (0)

    // wave wv stages its quarter (64 float4 = 1 KB) of each plane's tile:
    // one DMA instruction per plane, contiguous global run per instruction.
#define STAGE(bufi, k)                                                       \
    do {                                                                     \
        const int g = pb * RTHREADS + (k) * RSTRIDE + wv * 64 + ln;          \
        gld_lds16(P[0] + g, &stage[bufi][0][wv * 64]);                       \
        gld_lds16(P[1] + g, &stage[bufi][1][wv * 64]);                       \
        gld_lds16(P[2] + g, &stage[bufi][2][wv * 64]);                       \
        gld_lds16(P[3] + g, &stage[bufi][3][wv * 64]);                       \
        gld_lds16(P[4] + g, &stage[bufi][4][wv * 64]);                       \
        gld_lds16(P[5] + g, &stage[bufi][5][wv * 64]);                       \
    } while (0)

#define WAIT6() do {                                                         \
        asm volatile("s_waitcnt vmcnt(6)" ::: "memory");                     \
        __builtin_amdgcn_sched_barrier(0); } while (0)
#define WAIT0() do {                                                         \
        asm volatile("s_waitcnt vmcnt(0)" ::: "memory");                     \
        __builtin_amdgcn_sched_barrier(0); } while (0)
#define BAR() asm volatile("s_barrier" ::: "memory")

    STAGE(0, 0);
#pragma unroll
    for (int k = 0; k < RITERS; ++k) {
        const int cb = k & 1;
        if (k < RITERS - 1) { STAGE(cb ^ 1, k + 1); WAIT6(); }
        else                { WAIT0(); }
        BAR();
        const float4 a0 = stage[cb][0][threadIdx.x];
        const float4 a1 = stage[cb][1][threadIdx.x];
        const float4 a2 = stage[cb][2][threadIdx.x];
        const float4 b0 = stage[cb][3][threadIdx.x];
        const float4 b1 = stage[cb][4][threadIdx.x];
        const float4 b2 = stage[cb][5][threadIdx.x];
        ACC1(a0.x, a1.x, a2.x, b0.x, b1.x, b2.x);
        ACC1(a0.y, a1.y, a2.y, b0.y, b1.y, b2.y);
        ACC1(a0.z, a1.z, a2.z, b0.z, b1.z, b2.z);
        ACC1(a0.w, a1.w, a2.w, b0.w, b1.w, b2.w);
        if (k < RITERS - 1) BAR();   // all waves done reading buf cb before
                                     // tile k+2 (same buffer) is issued
    }
#undef STAGE
#undef WAIT6
#undef WAIT0
#undef BAR
#undef ACC1

    // wave (64-lane) butterfly reduce each stat in fp64
    double accd[NSTAT];
#pragma unroll
    for (int s = 0; s < NSTAT; ++s) {
        double v = (double)acc[s];
        for (int off = 32; off > 0; off >>= 1) v += __shfl_down(v, off, 64);
        accd[s] = v;
    }

    __shared__ double part[RTHREADS / 64][NSTAT];
    if (ln == 0) {
#pragma unroll
        for (int s = 0; s < NSTAT; ++s) part[wv][s] = accd[s];
    }
    __syncthreads();

    if (threadIdx.x < NSTAT) {
        const int s = threadIdx.x;
        double v = part[0][s] + part[1][s] + part[2][s] + part[3][s];
        partials[((size_t)b * NSTAT + s) * RBLOCKS + pb] = v;
    }
}

// ---------------------------------------------------------------------------
// Pass 2: reduce partials + 3x3 solve per batch. coef[b][12] fp32:
//   0..8 = x row-major, 9..11 = offset_c = bm_c - sum_j x[c][j]*am_j
// (unchanged — passing since round 4)
// ---------------------------------------------------------------------------
__global__ __launch_bounds__(RBLOCKS) void solve3x3(
    const double* __restrict__ partials, float* __restrict__ coef)
{
    const int b = blockIdx.x;
    const int t = threadIdx.x;  // RBLOCKS threads, 2 waves

    __shared__ double wsum[NSTAT][2];

#pragma unroll
    for (int s = 0; s < NSTAT; ++s) {
        double v = partials[((size_t)b * NSTAT + s) * RBLOCKS + t];
        for (int off = 32; off > 0; off >>= 1) v += __shfl_down(v, off, 64);
        if ((t & 63) == 0) wsum[s][t >> 6] = v;
    }
    __syncthreads();

    if (t == 0) {
        double st[NSTAT];
#pragma unroll
        for (int s = 0; s < NSTAT; ++s) st[s] = wsum[s][0] + wsum[s][1];

        const double N = (double)NPIX;
        double am[3] = {st[0] / N, st[1] / N, st[2] / N};
        double bm[3] = {st[3] / N, st[4] / N, st[5] / N};

        double AA[3][3];
        AA[0][0] = st[6]  - N * am[0] * am[0] + 0.001;
        AA[0][1] = st[7]  - N * am[0] * am[1];
        AA[0][2] = st[8]  - N * am[0] * am[2];
        AA[1][1] = st[9]  - N * am[1] * am[1] + 0.001;
        AA[1][2] = st[10] - N * am[1] * am[2];
        AA[2][2] = st[11] - N * am[2] * am[2] + 0.001;
        AA[1][0] = AA[0][1]; AA[2][0] = AA[0][2]; AA[2][1] = AA[1][2];

        double BA[3][3];
#pragma unroll
        for (int i = 0; i < 3; ++i)
#pragma unroll
            for (int j = 0; j < 3; ++j)
                BA[i][j] = st[12 + 3 * i + j] - N * bm[i] * am[j];

        // 3x3 inverse via adjugate
        double c00 =  AA[1][1] * AA[2][2] - AA[1][2] * AA[2][1];
        double c01 = -(AA[1][0] * AA[2][2] - AA[1][2] * AA[2][0]);
        double c02 =  AA[1][0] * AA[2][1] - AA[1][1] * AA[2][0];
        double det = AA[0][0] * c00 + AA[0][1] * c01 + AA[0][2] * c02;
        double id  = 1.0 / det;

        double inv[3][3];
        inv[0][0] = c00 * id;
        inv[1][0] = c01 * id;
        inv[2][0] = c02 * id;
        inv[0][1] = -(AA[0][1] * AA[2][2] - AA[0][2] * AA[2][1]) * id;
        inv[1][1] =  (AA[0][0] * AA[2][2] - AA[0][2] * AA[2][0]) * id;
        inv[2][1] = -(AA[0][0] * AA[2][1] - AA[0][1] * AA[2][0]) * id;
        inv[0][2] =  (AA[0][1] * AA[1][2] - AA[0][2] * AA[1][1]) * id;
        inv[1][2] = -(AA[0][0] * AA[1][2] - AA[0][2] * AA[1][0]) * id;
        inv[2][2] =  (AA[0][0] * AA[1][1] - AA[0][1] * AA[1][0]) * id;

        double X[3][3];
#pragma unroll
        for (int i = 0; i < 3; ++i)
#pragma unroll
            for (int j = 0; j < 3; ++j)
                X[i][j] = BA[i][0] * inv[0][j] + BA[i][1] * inv[1][j] +
                          BA[i][2] * inv[2][j];

        float* cb = coef + b * 12;
#pragma unroll
        for (int i = 0; i < 3; ++i) {
#pragma unroll
            for (int j = 0; j < 3; ++j) cb[3 * i + j] = (float)X[i][j];
            cb[9 + i] = (float)(bm[i] - (X[i][0] * am[0] + X[i][1] * am[1] +
                                         X[i][2] * am[2]));
        }
    }
}

// ---------------------------------------------------------------------------
// Pass 3: out[b][c][n] = sum_j x[c][j]*src[b][j][n] + offset[c]
// Unchanged from rounds 10/11 (passing) — CONTROL for this experiment.
// ---------------------------------------------------------------------------
__global__ __launch_bounds__(256, 2) void apply_map(
    const float4* __restrict__ src, float4* __restrict__ out,
    const float* __restrict__ coef)
{
    const int b = blockIdx.y;
    const float* cb = coef + b * 12;
    const float x00 = cb[0], x01 = cb[1], x02 = cb[2];
    const float x10 = cb[3], x11 = cb[4], x12 = cb[5];
    const float x20 = cb[6], x21 = cb[7], x22 = cb[8];
    const float o0 = cb[9], o1 = cb[10], o2 = cb[11];

    const float4* A0 = src + (size_t)b * 3 * NVEC;
    const float4* A1 = A0 + NVEC;
    const float4* A2 = A0 + 2 * NVEC;
    float4* O0 = out + (size_t)b * 3 * NVEC;
    float4* O1 = O0 + NVEC;
    float4* O2 = O0 + 2 * NVEC;

    const int p0 = blockIdx.x * 256 + threadIdx.x;

#define ALOAD(s, k)                                                          \
    do {                                                                     \
        const int pp = p0 + (k) * RSTRIDE;                                   \
        s##0 = A0[pp]; s##1 = A1[pp]; s##2 = A2[pp];                         \
    } while (0)

#define ASTORE(s, k)                                                         \
    do {                                                                     \
        const int pp = p0 + (k) * RSTRIDE;                                   \
        float4 r0, r1, r2;                                                   \
        r0.x = fmaf(x00, (s##0).x, fmaf(x01, (s##1).x, fmaf(x02, (s##2).x, o0))); \
        r1.x = fmaf(x10, (s##0).x, fmaf(x11, (s##1).x, fmaf(x12, (s##2).x, o1))); \
        r2.x = fmaf(x20, (s##0).x, fmaf(x21, (s##1).x, fmaf(x22, (s##2).x, o2))); \
        r0.y = fmaf(x00, (s##0).y, fmaf(x01, (s##1).y, fmaf(x02, (s##2).y, o0))); \
        r1.y = fmaf(x10, (s##0).y, fmaf(x11, (s##1).y, fmaf(x12, (s##2).y, o1))); \
        r2.y = fmaf(x20, (s##0).y, fmaf(x21, (s##1).y, fmaf(x22, (s##2).y, o2))); \
        r0.z = fmaf(x00, (s##0).z, fmaf(x01, (s##1).z, fmaf(x02, (s##2).z, o0))); \
        r1.z = fmaf(x10, (s##0).z, fmaf(x11, (s##1).z, fmaf(x12, (s##2).z, o1))); \
        r2.z = fmaf(x20, (s##0).z, fmaf(x21, (s##1).z, fmaf(x22, (s##2).z, o2))); \
        r0.w = fmaf(x00, (s##0).w, fmaf(x01, (s##1).w, fmaf(x02, (s##2).w, o0))); \
        r1.w = fmaf(x10, (s##0).w, fmaf(x11, (s##1).w, fmaf(x12, (s##2).w, o1))); \
        r2.w = fmaf(x20, (s##0).w, fmaf(x21, (s##1).w, fmaf(x22, (s##2).w, o2))); \
        O0[pp] = r0; O1[pp] = r1; O2[pp] = r2;                               \
    } while (0)

    float4 u0, u1, u2;
    float4 v0, v1, v2;
    float4 w0, w1, w2;

    // RITERS == 8; rotation u,v,w,u,v,w,u,v; prefetch 2 ahead.
    ALOAD(u, 0);
    ALOAD(v, 1);
    ALOAD(w, 2);  ASTORE(u, 0);
    ALOAD(u, 3);  ASTORE(v, 1);
    ALOAD(v, 4);  ASTORE(w, 2);
    ALOAD(w, 5);  ASTORE(u, 3);
    ALOAD(u, 6);  ASTORE(v, 4);
    ALOAD(v, 7);  ASTORE(w, 5);
                  ASTORE(u, 6);
                  ASTORE(v, 7);
#undef ALOAD
#undef ASTORE
}

extern "C" void kernel_launch(void* const* d_in, const int* in_sizes, int n_in,
                              void* d_out, int out_size, void* d_ws, size_t ws_size,
                              hipStream_t stream)
{
    const float4* src = (const float4*)d_in[0];
    const float4* dst = (const float4*)d_in[1];
    float4* out = (float4*)d_out;

    const int batches = in_sizes[0] / (3 * NPIX);  // 16

    double* partials = (double*)d_ws;
    float*  coef = (float*)((char*)d_ws +
                            (size_t)batches * NSTAT * RBLOCKS * sizeof(double));

    reduce_stats<<<dim3(RBLOCKS, batches), RTHREADS, 0, stream>>>(src, dst, partials);
    solve3x3<<<batches, RBLOCKS, 0, stream>>>(partials, (float*)coef);
    apply_map<<<dim3(RBLOCKS, batches), 256, 0, stream>>>(src, out, coef);
}